// Round 8
// baseline (103.264 us; speedup 1.0000x reference)
//
#include <hip/hip_runtime.h>
#include <hip/hip_fp16.h>
#include <math.h>

// rbfLayer: N=100k points, DEG=16 neighbors, NB=MB=4 bases, FIN=FOUT=8.
// out[u,i] = sum_{e,n,m,j} c_e[n] f_e[m] K[i,j,n,m] feat[nbr_e, j]
// Per-point moment tensor G[n,m,j], then one K-contraction per point.
// 4 threads/point: (j-half) x (edge-half), 8 edges/thread.
// Packed 32B record/point: [px f32, py f32, f0..f3 f16 | f4..f7 f16, pad].
// NEW: the lane pair (half=0/1) loads the record's two float4 halves with ONE
// divergent-address instruction (same 64B line -> 1 TA request per edge);
// half=1 recovers (px,py) via 2 shfl_xor placed BEFORE trig (cheap, off the
// critical FMA path -- unlike R5's post-trig 8-shuffle chain that regressed).

#define TWO_OVER_PI 0.63661977236758134f

__device__ __forceinline__ float fast_atan2f(float y, float x) {
    float ax = fabsf(x), ay = fabsf(y);
    float mx = fmaxf(ax, ay);
    float mn = fminf(ax, ay);
    mx = fmaxf(mx, 1e-30f);                      // guard rcp(0)
    float r = mn * __builtin_amdgcn_rcpf(mx);
    float s = r * r;
    float p = -0.0117212f;                       // minimax atan on [0,1]
    p = fmaf(p, s,  0.05265332f);
    p = fmaf(p, s, -0.11643287f);
    p = fmaf(p, s,  0.19354346f);
    p = fmaf(p, s, -0.33262347f);
    p = fmaf(p, s,  0.99997726f);
    float a = p * r;
    a = (ay > ax) ? (1.57079632679f - a) : a;    // fold octant
    a = (x < 0.0f) ? (3.14159265359f - a) : a;   // fold quadrant
    return copysignf(a, y);
}

__device__ __forceinline__ void edge_basis(float dx, float dy,
                                           float c[4], float f[4]) {
    float dist = sqrtf(fmaf(dx, dx, dy * dy));
    float tr = dist * 1.5f;                       // radial hat coordinate
    float theta = fast_atan2f(dy, dx);
    float ta = fmaf(theta, TWO_OVER_PI, 2.0f);    // angular in [0,4]
#pragma unroll
    for (int n = 0; n < 4; ++n)
        c[n] = fmaxf(1.0f - fabsf(tr - (float)n), 0.0f);
#pragma unroll
    for (int m = 0; m < 4; ++m) {
        float d = fabsf(ta - (float)m);
        d = fminf(d, 4.0f - d);                   // periodic wrap (period 4)
        f[m] = fmaxf(1.0f - d, 0.0f);
    }
}

__device__ __forceinline__ float2 h2f(float bits) {
    union { float f; __half2 h; } u;
    u.f = bits;
    return make_float2(__low2float(u.h), __high2float(u.h));
}

__device__ __forceinline__ float h2f_pack(float a, float b) {
    union { __half2 h; float f; } u;
    u.h = __floats2half2_rn(a, b);
    return u.f;
}

// ---- Pre-pass: packed[u*2]   = { px, py, h(f0,f1), h(f2,f3) }
//                packed[u*2+1] = { h(f4,f5), h(f6,f7), 0, 0 }
__global__ __launch_bounds__(256) void pack_kernel(
    const float* __restrict__ positions,
    const float* __restrict__ features,
    float4*      __restrict__ packed,    // 2 float4 per point (32B record)
    int npts)
{
    int u = blockIdx.x * blockDim.x + threadIdx.x;
    if (u >= npts) return;
    float2 p  = ((const float2*)positions)[u];
    float4 fa = ((const float4*)features)[u * 2];
    float4 fb = ((const float4*)features)[u * 2 + 1];
    float4 q0, q1;
    q0.x = p.x;
    q0.y = p.y;
    q0.z = h2f_pack(fa.x, fa.y);
    q0.w = h2f_pack(fa.z, fa.w);
    q1.x = h2f_pack(fb.x, fb.y);
    q1.y = h2f_pack(fb.z, fb.w);
    q1.z = 0.0f;
    q1.w = 0.0f;
    packed[u * 2]     = q0;
    packed[u * 2 + 1] = q1;
}

// ---- Main kernel (packed path, split-record pair load)
__global__ __launch_bounds__(256) void rbf_packed_kernel(
    const float* __restrict__ positions,
    const float4* __restrict__ packed,
    const float* __restrict__ kern,
    const int*   __restrict__ neighbors,
    const int*   __restrict__ row_splits,
    float*       __restrict__ out,
    int npts)
{
    __shared__ float Kl[1024];   // K[i][j][n][m], i*128 + j*16 + n*4 + m
    {
        const float4* src = (const float4*)kern;
        float4* dst = (float4*)Kl;
        dst[threadIdx.x] = src[threadIdx.x];
    }
    __syncthreads();

    int gt   = blockIdx.x * blockDim.x + threadIdx.x;
    int u    = gt >> 2;
    int sub  = gt & 3;
    int half = sub & 1;      // j-half: feature/K columns [half*4, half*4+4)
    int eh   = sub >> 1;     // edge-half: edges [rs0+eh*8, rs0+eh*8+8)
    if (u >= npts) return;

    float2 pu = ((const float2*)positions)[u];
    int rs0 = row_splits[u];
    int rs1 = row_splits[u + 1];
    int cnt = rs1 - rs0;

    float g[16][4];
#pragma unroll
    for (int nm = 0; nm < 16; ++nm)
#pragma unroll
        for (int j = 0; j < 4; ++j) g[nm][j] = 0.0f;

    if (cnt == 16) {
        int e0 = rs0 + eh * 8;
        const int4* nb4 = (const int4*)(neighbors + e0);
        int4 nA = nb4[0];
        int4 nB = nb4[1];

        // Lane pair (half=0, half=1) splits each 32B record: one divergent
        // instruction hits one 64B line -> 1 request/edge.
#define VISIT_SPLIT(R)                                                        \
        {                                                                     \
            float sx = __shfl_xor(R.x, 1);                                    \
            float sy = __shfl_xor(R.y, 1);                                    \
            float px = half ? sx : R.x;                                       \
            float py = half ? sy : R.y;                                       \
            float c[4], f[4];                                                 \
            edge_basis(px - pu.x, py - pu.y, c, f);                           \
            float2 lo = h2f(half ? R.x : R.z);                                \
            float2 hi = h2f(half ? R.y : R.w);                                \
            float fvj[4] = {lo.x, lo.y, hi.x, hi.y};                          \
            _Pragma("unroll")                                                 \
            for (int n = 0; n < 4; ++n)                                       \
                _Pragma("unroll")                                             \
                for (int m = 0; m < 4; ++m) {                                 \
                    float w = c[n] * f[m];                                    \
                    _Pragma("unroll")                                         \
                    for (int j = 0; j < 4; ++j)                               \
                        g[n * 4 + m][j] = fmaf(w, fvj[j], g[n * 4 + m][j]);   \
                }                                                             \
        }

#pragma unroll
        for (int grp = 0; grp < 2; ++grp) {
            int nb0 = grp ? nB.x : nA.x;
            int nb1 = grp ? nB.y : nA.y;
            int nb2 = grp ? nB.z : nA.z;
            int nb3 = grp ? nB.w : nA.w;
            // 4 loads issued up front; each is one 16B divergent-pair load.
            float4 R0 = packed[nb0 * 2 + half];
            float4 R1 = packed[nb1 * 2 + half];
            float4 R2 = packed[nb2 * 2 + half];
            float4 R3 = packed[nb3 * 2 + half];
            VISIT_SPLIT(R0)
            VISIT_SPLIT(R1)
            VISIT_SPLIT(R2)
            VISIT_SPLIT(R3)
        }
#undef VISIT_SPLIT
    } else {
        // Generic path (uniform DEG=16 never takes this; kept for safety).
        // Direct 2-load version, no shuffles.
        int c0 = (cnt + 1) >> 1;
        int e0 = rs0 + eh * c0;
        int e1 = (eh == 0) ? (rs0 + c0) : rs1;
        for (int e = e0; e < e1; ++e) {
            int nb = neighbors[e];
            float4 A = packed[nb * 2];
            float4 C = packed[nb * 2 + 1];
            float c[4], f[4];
            edge_basis(A.x - pu.x, A.y - pu.y, c, f);
            float2 lo = h2f(half ? C.x : A.z);
            float2 hi = h2f(half ? C.y : A.w);
            float fvj[4] = {lo.x, lo.y, hi.x, hi.y};
#pragma unroll
            for (int n = 0; n < 4; ++n)
#pragma unroll
                for (int m = 0; m < 4; ++m) {
                    float w = c[n] * f[m];
#pragma unroll
                    for (int j = 0; j < 4; ++j)
                        g[n * 4 + m][j] = fmaf(w, fvj[j], g[n * 4 + m][j]);
                }
        }
    }

    // Final contraction: o[i] = sum_{j in half, nm} K[i, jg, nm] * g[nm][j]
    float o[8];
#pragma unroll
    for (int i = 0; i < 8; ++i) o[i] = 0.0f;

    const float4* K4 = (const float4*)Kl;
#pragma unroll
    for (int i = 0; i < 8; ++i) {
#pragma unroll
        for (int j = 0; j < 4; ++j) {
            int jg = half * 4 + j;
            int base4 = (i * 128 + jg * 16) >> 2;
#pragma unroll
            for (int q = 0; q < 4; ++q) {
                float4 kv = K4[base4 + q];
                o[i] = fmaf(kv.x, g[q * 4 + 0][j], o[i]);
                o[i] = fmaf(kv.y, g[q * 4 + 1][j], o[i]);
                o[i] = fmaf(kv.z, g[q * 4 + 2][j], o[i]);
                o[i] = fmaf(kv.w, g[q * 4 + 3][j], o[i]);
            }
        }
    }

#pragma unroll
    for (int i = 0; i < 8; ++i) {
        o[i] += __shfl_xor(o[i], 1);
        o[i] += __shfl_xor(o[i], 2);
    }

    float2 ov = (sub == 0) ? make_float2(o[0], o[1])
              : (sub == 1) ? make_float2(o[2], o[3])
              : (sub == 2) ? make_float2(o[4], o[5])
                           : make_float2(o[6], o[7]);
    ((float2*)out)[u * 4 + sub] = ov;
}

// ---- Fallback (no workspace): direct gathers, full fp32.
__global__ __launch_bounds__(256) void rbf_direct_kernel(
    const float* __restrict__ positions,
    const float* __restrict__ features,
    const float* __restrict__ kern,
    const int*   __restrict__ neighbors,
    const int*   __restrict__ row_splits,
    float*       __restrict__ out,
    int npts)
{
    __shared__ float Kl[1024];
    {
        const float4* src = (const float4*)kern;
        float4* dst = (float4*)Kl;
        dst[threadIdx.x] = src[threadIdx.x];
    }
    __syncthreads();

    int gt   = blockIdx.x * blockDim.x + threadIdx.x;
    int u    = gt >> 2;
    int sub  = gt & 3;
    int half = sub & 1;
    int eh   = sub >> 1;
    if (u >= npts) return;

    float2 pu = ((const float2*)positions)[u];
    int rs0 = row_splits[u];
    int rs1 = row_splits[u + 1];
    int cnt = rs1 - rs0;

    float g[16][4];
#pragma unroll
    for (int nm = 0; nm < 16; ++nm)
#pragma unroll
        for (int j = 0; j < 4; ++j) g[nm][j] = 0.0f;

    const float2* pos2  = (const float2*)positions;
    const float4* feat4 = (const float4*)features;

    int c0 = (cnt + 1) >> 1;
    int e0 = rs0 + eh * c0;
    int e1 = (eh == 0) ? (rs0 + c0) : rs1;
    for (int e = e0; e < e1; ++e) {
        int nb = neighbors[e];
        float2 pn = pos2[nb];
        float c[4], f[4];
        edge_basis(pn.x - pu.x, pn.y - pu.y, c, f);
        float4 fv = feat4[nb * 2 + half];
        float fvj[4] = {fv.x, fv.y, fv.z, fv.w};
#pragma unroll
        for (int n = 0; n < 4; ++n)
#pragma unroll
            for (int m = 0; m < 4; ++m) {
                float w = c[n] * f[m];
#pragma unroll
                for (int j = 0; j < 4; ++j)
                    g[n * 4 + m][j] = fmaf(w, fvj[j], g[n * 4 + m][j]);
            }
    }

    float o[8];
#pragma unroll
    for (int i = 0; i < 8; ++i) o[i] = 0.0f;
    const float4* K4 = (const float4*)Kl;
#pragma unroll
    for (int i = 0; i < 8; ++i) {
#pragma unroll
        for (int j = 0; j < 4; ++j) {
            int jg = half * 4 + j;
            int base4 = (i * 128 + jg * 16) >> 2;
#pragma unroll
            for (int q = 0; q < 4; ++q) {
                float4 kv = K4[base4 + q];
                o[i] = fmaf(kv.x, g[q * 4 + 0][j], o[i]);
                o[i] = fmaf(kv.y, g[q * 4 + 1][j], o[i]);
                o[i] = fmaf(kv.z, g[q * 4 + 2][j], o[i]);
                o[i] = fmaf(kv.w, g[q * 4 + 3][j], o[i]);
            }
        }
    }
#pragma unroll
    for (int i = 0; i < 8; ++i) {
        o[i] += __shfl_xor(o[i], 1);
        o[i] += __shfl_xor(o[i], 2);
    }
    float2 ov = (sub == 0) ? make_float2(o[0], o[1])
              : (sub == 1) ? make_float2(o[2], o[3])
              : (sub == 2) ? make_float2(o[4], o[5])
                           : make_float2(o[6], o[7]);
    ((float2*)out)[u * 4 + sub] = ov;
}

extern "C" void kernel_launch(void* const* d_in, const int* in_sizes, int n_in,
                              void* d_out, int out_size, void* d_ws, size_t ws_size,
                              hipStream_t stream) {
    const float* positions  = (const float*)d_in[0];
    const float* features   = (const float*)d_in[1];
    const float* kern       = (const float*)d_in[2];
    const int*   neighbors  = (const int*)d_in[3];
    const int*   row_splits = (const int*)d_in[4];
    float* out = (float*)d_out;

    int npts = in_sizes[0] / 2;
    int total = npts * 4;
    int block = 256;
    int grid = (total + block - 1) / block;

    size_t need = (size_t)npts * 32;   // 32B packed record per point
    if (ws_size >= need) {
        int pgrid = (npts + block - 1) / block;
        pack_kernel<<<pgrid, block, 0, stream>>>(positions, features,
                                                 (float4*)d_ws, npts);
        rbf_packed_kernel<<<grid, block, 0, stream>>>(positions,
                                                      (const float4*)d_ws, kern,
                                                      neighbors, row_splits,
                                                      out, npts);
    } else {
        rbf_direct_kernel<<<grid, block, 0, stream>>>(positions, features, kern,
                                                      neighbors, row_splits,
                                                      out, npts);
    }
}

// Round 10
// 101.893 us; speedup vs baseline: 1.0135x; 1.0135x over previous
//
#include <hip/hip_runtime.h>
#include <hip/hip_fp16.h>
#include <math.h>

// rbfLayer: N=100k points, DEG=16 neighbors, NB=MB=4 bases, FIN=FOUT=8.
// out[u,i] = sum_{e,n,m,j} c_e[n] f_e[m] K[i,j,n,m] feat[nbr_e, j]
// Per-point moment tensor G[n,m,j], then one K-contraction per point.
// 4 threads/point: (j-half) x (edge-half), 8 edges/thread.
// Packed 32B record/point, SELF-CONTAINED 16B halves (positions duplicated):
//   packed[u*2+0] = { px, py, h(f0,f1), h(f2,f3) }
//   packed[u*2+1] = { px, py, h(f4,f5), h(f6,f7) }
// -> ONE float4 load per edge per lane, zero shuffles (R5/R8 lesson: any
// shfl in the edge loop costs ~10us), pair lanes share one 64B line.

#define TWO_OVER_PI 0.63661977236758134f

__device__ __forceinline__ float fast_atan2f(float y, float x) {
    float ax = fabsf(x), ay = fabsf(y);
    float mx = fmaxf(ax, ay);
    float mn = fminf(ax, ay);
    mx = fmaxf(mx, 1e-30f);                      // guard rcp(0)
    float r = mn * __builtin_amdgcn_rcpf(mx);
    float s = r * r;
    float p = -0.0117212f;                       // minimax atan on [0,1]
    p = fmaf(p, s,  0.05265332f);
    p = fmaf(p, s, -0.11643287f);
    p = fmaf(p, s,  0.19354346f);
    p = fmaf(p, s, -0.33262347f);
    p = fmaf(p, s,  0.99997726f);
    float a = p * r;
    a = (ay > ax) ? (1.57079632679f - a) : a;    // fold octant
    a = (x < 0.0f) ? (3.14159265359f - a) : a;   // fold quadrant
    return copysignf(a, y);
}

__device__ __forceinline__ void edge_basis(float dx, float dy,
                                           float c[4], float f[4]) {
    float dist = sqrtf(fmaf(dx, dx, dy * dy));
    float tr = dist * 1.5f;                       // radial hat coordinate
    float theta = fast_atan2f(dy, dx);
    float ta = fmaf(theta, TWO_OVER_PI, 2.0f);    // angular in [0,4]
#pragma unroll
    for (int n = 0; n < 4; ++n)
        c[n] = fmaxf(1.0f - fabsf(tr - (float)n), 0.0f);
#pragma unroll
    for (int m = 0; m < 4; ++m) {
        float d = fabsf(ta - (float)m);
        d = fminf(d, 4.0f - d);                   // periodic wrap (period 4)
        f[m] = fmaxf(1.0f - d, 0.0f);
    }
}

__device__ __forceinline__ float2 h2f(float bits) {
    union { float f; __half2 h; } u;
    u.f = bits;
    return make_float2(__low2float(u.h), __high2float(u.h));
}

__device__ __forceinline__ float h2f_pack(float a, float b) {
    union { __half2 h; float f; } u;
    u.h = __floats2half2_rn(a, b);
    return u.f;
}

// ---- Pre-pass: self-contained 16B halves, positions duplicated.
__global__ __launch_bounds__(256) void pack_kernel(
    const float* __restrict__ positions,
    const float* __restrict__ features,
    float4*      __restrict__ packed,    // 2 float4 per point (32B record)
    int npts)
{
    int u = blockIdx.x * blockDim.x + threadIdx.x;
    if (u >= npts) return;
    float2 p  = ((const float2*)positions)[u];
    float4 fa = ((const float4*)features)[u * 2];
    float4 fb = ((const float4*)features)[u * 2 + 1];
    float4 q0, q1;
    q0.x = p.x;
    q0.y = p.y;
    q0.z = h2f_pack(fa.x, fa.y);
    q0.w = h2f_pack(fa.z, fa.w);
    q1.x = p.x;
    q1.y = p.y;
    q1.z = h2f_pack(fb.x, fb.y);
    q1.w = h2f_pack(fb.z, fb.w);
    packed[u * 2]     = q0;
    packed[u * 2 + 1] = q1;
}

// ---- Main kernel: 1 self-contained load per edge, all loads hoisted.
__global__ __launch_bounds__(256) void rbf_packed_kernel(
    const float* __restrict__ positions,
    const float4* __restrict__ packed,
    const float* __restrict__ kern,
    const int*   __restrict__ neighbors,
    const int*   __restrict__ row_splits,
    float*       __restrict__ out,
    int npts)
{
    __shared__ float Kl[1024];   // K[i][j][n][m], i*128 + j*16 + n*4 + m
    {
        const float4* src = (const float4*)kern;
        float4* dst = (float4*)Kl;
        dst[threadIdx.x] = src[threadIdx.x];
    }
    __syncthreads();

    int gt   = blockIdx.x * blockDim.x + threadIdx.x;
    int u    = gt >> 2;
    int sub  = gt & 3;
    int half = sub & 1;      // j-half: feature/K columns [half*4, half*4+4)
    int eh   = sub >> 1;     // edge-half: edges [rs0+eh*8, rs0+eh*8+8)
    if (u >= npts) return;

    float2 pu = ((const float2*)positions)[u];
    int rs0 = row_splits[u];
    int rs1 = row_splits[u + 1];
    int cnt = rs1 - rs0;

    float g[16][4];
#pragma unroll
    for (int nm = 0; nm < 16; ++nm)
#pragma unroll
        for (int j = 0; j < 4; ++j) g[nm][j] = 0.0f;

#define VISIT(R)                                                              \
    {                                                                         \
        float c[4], f[4];                                                     \
        edge_basis(R.x - pu.x, R.y - pu.y, c, f);                             \
        float2 lo = h2f(R.z);                                                 \
        float2 hi = h2f(R.w);                                                 \
        float fvj[4] = {lo.x, lo.y, hi.x, hi.y};                              \
        _Pragma("unroll")                                                     \
        for (int n = 0; n < 4; ++n)                                           \
            _Pragma("unroll")                                                 \
            for (int m = 0; m < 4; ++m) {                                     \
                float w = c[n] * f[m];                                        \
                _Pragma("unroll")                                             \
                for (int j = 0; j < 4; ++j)                                   \
                    g[n * 4 + m][j] = fmaf(w, fvj[j], g[n * 4 + m][j]);       \
            }                                                                 \
    }

    if (cnt == 16) {
        int e0 = rs0 + eh * 8;
        const int4* nb4 = (const int4*)(neighbors + e0);
        int4 nA = nb4[0];
        int4 nB = nb4[1];

        // All 8 self-contained record loads issued before any compute:
        // 8-deep MLP window, 1 line per edge (pair lanes coalesce).
        float4 R0 = packed[nA.x * 2 + half];
        float4 R1 = packed[nA.y * 2 + half];
        float4 R2 = packed[nA.z * 2 + half];
        float4 R3 = packed[nA.w * 2 + half];
        float4 R4 = packed[nB.x * 2 + half];
        float4 R5 = packed[nB.y * 2 + half];
        float4 R6 = packed[nB.z * 2 + half];
        float4 R7 = packed[nB.w * 2 + half];

        VISIT(R0)
        VISIT(R1)
        VISIT(R2)
        VISIT(R3)
        VISIT(R4)
        VISIT(R5)
        VISIT(R6)
        VISIT(R7)
    } else {
        // Generic path (uniform DEG=16 never takes this; kept for safety).
        int c0 = (cnt + 1) >> 1;
        int e0 = rs0 + eh * c0;
        int e1 = (eh == 0) ? (rs0 + c0) : rs1;
        for (int e = e0; e < e1; ++e) {
            int nb = neighbors[e];
            float4 R = packed[nb * 2 + half];
            VISIT(R)
        }
    }
#undef VISIT

    // Final contraction: o[i] = sum_{j in half, nm} K[i, jg, nm] * g[nm][j]
    float o[8];
#pragma unroll
    for (int i = 0; i < 8; ++i) o[i] = 0.0f;

    const float4* K4 = (const float4*)Kl;
#pragma unroll
    for (int i = 0; i < 8; ++i) {
#pragma unroll
        for (int j = 0; j < 4; ++j) {
            int jg = half * 4 + j;
            int base4 = (i * 128 + jg * 16) >> 2;
#pragma unroll
            for (int q = 0; q < 4; ++q) {
                float4 kv = K4[base4 + q];
                o[i] = fmaf(kv.x, g[q * 4 + 0][j], o[i]);
                o[i] = fmaf(kv.y, g[q * 4 + 1][j], o[i]);
                o[i] = fmaf(kv.z, g[q * 4 + 2][j], o[i]);
                o[i] = fmaf(kv.w, g[q * 4 + 3][j], o[i]);
            }
        }
    }

    // Reduce over the 4 lanes of this point (epilogue only — cheap).
#pragma unroll
    for (int i = 0; i < 8; ++i) {
        o[i] += __shfl_xor(o[i], 1);
        o[i] += __shfl_xor(o[i], 2);
    }

    float2 ov = (sub == 0) ? make_float2(o[0], o[1])
              : (sub == 1) ? make_float2(o[2], o[3])
              : (sub == 2) ? make_float2(o[4], o[5])
                           : make_float2(o[6], o[7]);
    ((float2*)out)[u * 4 + sub] = ov;
}

// ---- Fallback (no workspace): direct gathers, full fp32.
__global__ __launch_bounds__(256) void rbf_direct_kernel(
    const float* __restrict__ positions,
    const float* __restrict__ features,
    const float* __restrict__ kern,
    const int*   __restrict__ neighbors,
    const int*   __restrict__ row_splits,
    float*       __restrict__ out,
    int npts)
{
    __shared__ float Kl[1024];
    {
        const float4* src = (const float4*)kern;
        float4* dst = (float4*)Kl;
        dst[threadIdx.x] = src[threadIdx.x];
    }
    __syncthreads();

    int gt   = blockIdx.x * blockDim.x + threadIdx.x;
    int u    = gt >> 2;
    int sub  = gt & 3;
    int half = sub & 1;
    int eh   = sub >> 1;
    if (u >= npts) return;

    float2 pu = ((const float2*)positions)[u];
    int rs0 = row_splits[u];
    int rs1 = row_splits[u + 1];
    int cnt = rs1 - rs0;

    float g[16][4];
#pragma unroll
    for (int nm = 0; nm < 16; ++nm)
#pragma unroll
        for (int j = 0; j < 4; ++j) g[nm][j] = 0.0f;

    const float2* pos2  = (const float2*)positions;
    const float4* feat4 = (const float4*)features;

    int c0 = (cnt + 1) >> 1;
    int e0 = rs0 + eh * c0;
    int e1 = (eh == 0) ? (rs0 + c0) : rs1;
    for (int e = e0; e < e1; ++e) {
        int nb = neighbors[e];
        float2 pn = pos2[nb];
        float c[4], f[4];
        edge_basis(pn.x - pu.x, pn.y - pu.y, c, f);
        float4 fv = feat4[nb * 2 + half];
        float fvj[4] = {fv.x, fv.y, fv.z, fv.w};
#pragma unroll
        for (int n = 0; n < 4; ++n)
#pragma unroll
            for (int m = 0; m < 4; ++m) {
                float w = c[n] * f[m];
#pragma unroll
                for (int j = 0; j < 4; ++j)
                    g[n * 4 + m][j] = fmaf(w, fvj[j], g[n * 4 + m][j]);
            }
    }

    float o[8];
#pragma unroll
    for (int i = 0; i < 8; ++i) o[i] = 0.0f;
    const float4* K4 = (const float4*)Kl;
#pragma unroll
    for (int i = 0; i < 8; ++i) {
#pragma unroll
        for (int j = 0; j < 4; ++j) {
            int jg = half * 4 + j;
            int base4 = (i * 128 + jg * 16) >> 2;
#pragma unroll
            for (int q = 0; q < 4; ++q) {
                float4 kv = K4[base4 + q];
                o[i] = fmaf(kv.x, g[q * 4 + 0][j], o[i]);
                o[i] = fmaf(kv.y, g[q * 4 + 1][j], o[i]);
                o[i] = fmaf(kv.z, g[q * 4 + 2][j], o[i]);
                o[i] = fmaf(kv.w, g[q * 4 + 3][j], o[i]);
            }
        }
    }
#pragma unroll
    for (int i = 0; i < 8; ++i) {
        o[i] += __shfl_xor(o[i], 1);
        o[i] += __shfl_xor(o[i], 2);
    }
    float2 ov = (sub == 0) ? make_float2(o[0], o[1])
              : (sub == 1) ? make_float2(o[2], o[3])
              : (sub == 2) ? make_float2(o[4], o[5])
                           : make_float2(o[6], o[7]);
    ((float2*)out)[u * 4 + sub] = ov;
}

extern "C" void kernel_launch(void* const* d_in, const int* in_sizes, int n_in,
                              void* d_out, int out_size, void* d_ws, size_t ws_size,
                              hipStream_t stream) {
    const float* positions  = (const float*)d_in[0];
    const float* features   = (const float*)d_in[1];
    const float* kern       = (const float*)d_in[2];
    const int*   neighbors  = (const int*)d_in[3];
    const int*   row_splits = (const int*)d_in[4];
    float* out = (float*)d_out;

    int npts = in_sizes[0] / 2;
    int total = npts * 4;
    int block = 256;
    int grid = (total + block - 1) / block;

    size_t need = (size_t)npts * 32;   // 32B packed record per point
    if (ws_size >= need) {
        int pgrid = (npts + block - 1) / block;
        pack_kernel<<<pgrid, block, 0, stream>>>(positions, features,
                                                 (float4*)d_ws, npts);
        rbf_packed_kernel<<<grid, block, 0, stream>>>(positions,
                                                      (const float4*)d_ws, kern,
                                                      neighbors, row_splits,
                                                      out, npts);
    } else {
        rbf_direct_kernel<<<grid, block, 0, stream>>>(positions, features, kern,
                                                      neighbors, row_splits,
                                                      out, npts);
    }
}

// Round 15
// 91.514 us; speedup vs baseline: 1.1284x; 1.1134x over previous
//
#include <hip/hip_runtime.h>
#include <hip/hip_fp16.h>
#include <math.h>

// rbfLayer: N=100k points, DEG=16 neighbors, NB=MB=4 bases, FIN=FOUT=8.
// out[u,i] = sum_{e,n,m,j} c_e[n] f_e[m] K[i,j,n,m] feat[nbr_e, j]
// Per-point moment tensor G, then one K-contraction per point.
// 4 threads/point: (j-half) x (edge-half), 8 edges/thread.
// Packed 32B record/point, self-contained 16B halves (positions duplicated):
//   packed[u*2+h] = { px, py, h(f_{4h}..), h(f_{4h+2}..) }
// -> ONE float4 load per edge per lane, zero loop shuffles, pair lanes share
// one 64B line.  R11: both hot loops use 2-wide packed FMA
// (v_pk_fma_f32 via __builtin_elementwise_fma) -> ~half the VALU issue.
// G storage: g2[j][p] = { G[2p][j], G[2p+1][j] }  (p = nm-pair, static idx).

#define TWO_OVER_PI 0.63661977236758134f

typedef float v2f __attribute__((ext_vector_type(2)));

__device__ __forceinline__ float fast_atan2f(float y, float x) {
    float ax = fabsf(x), ay = fabsf(y);
    float mx = fmaxf(ax, ay);
    float mn = fminf(ax, ay);
    mx = fmaxf(mx, 1e-30f);                      // guard rcp(0)
    float r = mn * __builtin_amdgcn_rcpf(mx);
    float s = r * r;
    float p = -0.0117212f;                       // minimax atan on [0,1]
    p = fmaf(p, s,  0.05265332f);
    p = fmaf(p, s, -0.11643287f);
    p = fmaf(p, s,  0.19354346f);
    p = fmaf(p, s, -0.33262347f);
    p = fmaf(p, s,  0.99997726f);
    float a = p * r;
    a = (ay > ax) ? (1.57079632679f - a) : a;    // fold octant
    a = (x < 0.0f) ? (3.14159265359f - a) : a;   // fold quadrant
    return copysignf(a, y);
}

__device__ __forceinline__ void edge_basis(float dx, float dy,
                                           float c[4], float f[4]) {
    float dist = sqrtf(fmaf(dx, dx, dy * dy));
    float tr = dist * 1.5f;                       // radial hat coordinate
    float theta = fast_atan2f(dy, dx);
    float ta = fmaf(theta, TWO_OVER_PI, 2.0f);    // angular in [0,4]
#pragma unroll
    for (int n = 0; n < 4; ++n)
        c[n] = fmaxf(1.0f - fabsf(tr - (float)n), 0.0f);
#pragma unroll
    for (int m = 0; m < 4; ++m) {
        float d = fabsf(ta - (float)m);
        d = fminf(d, 4.0f - d);                   // periodic wrap (period 4)
        f[m] = fmaxf(1.0f - d, 0.0f);
    }
}

__device__ __forceinline__ float2 h2f(float bits) {
    union { float f; __half2 h; } u;
    u.f = bits;
    return make_float2(__low2float(u.h), __high2float(u.h));
}

__device__ __forceinline__ float h2f_pack(float a, float b) {
    union { __half2 h; float f; } u;
    u.h = __floats2half2_rn(a, b);
    return u.f;
}

// ---- Pre-pass: self-contained 16B halves, positions duplicated.
__global__ __launch_bounds__(256) void pack_kernel(
    const float* __restrict__ positions,
    const float* __restrict__ features,
    float4*      __restrict__ packed,    // 2 float4 per point (32B record)
    int npts)
{
    int u = blockIdx.x * blockDim.x + threadIdx.x;
    if (u >= npts) return;
    float2 p  = ((const float2*)positions)[u];
    float4 fa = ((const float4*)features)[u * 2];
    float4 fb = ((const float4*)features)[u * 2 + 1];
    float4 q0, q1;
    q0.x = p.x;
    q0.y = p.y;
    q0.z = h2f_pack(fa.x, fa.y);
    q0.w = h2f_pack(fa.z, fa.w);
    q1.x = p.x;
    q1.y = p.y;
    q1.z = h2f_pack(fb.x, fb.y);
    q1.w = h2f_pack(fb.z, fb.w);
    packed[u * 2]     = q0;
    packed[u * 2 + 1] = q1;
}

// ---- Main kernel: 1 self-contained load per edge, packed-FMA math.
__global__ __launch_bounds__(256) void rbf_packed_kernel(
    const float* __restrict__ positions,
    const float4* __restrict__ packed,
    const float* __restrict__ kern,
    const int*   __restrict__ neighbors,
    const int*   __restrict__ row_splits,
    float*       __restrict__ out,
    int npts)
{
    __shared__ float Kl[1024];   // K[i][j][n][m], i*128 + j*16 + n*4 + m
    {
        const float4* src = (const float4*)kern;
        float4* dst = (float4*)Kl;
        dst[threadIdx.x] = src[threadIdx.x];
    }
    __syncthreads();

    int gt   = blockIdx.x * blockDim.x + threadIdx.x;
    int u    = gt >> 2;
    int sub  = gt & 3;
    int half = sub & 1;      // j-half: feature/K columns [half*4, half*4+4)
    int eh   = sub >> 1;     // edge-half: edges [rs0+eh*8, rs0+eh*8+8)
    if (u >= npts) return;

    float2 pu = ((const float2*)positions)[u];
    int rs0 = row_splits[u];
    int rs1 = row_splits[u + 1];
    int cnt = rs1 - rs0;

    // g2[j][p] = { G[2p][j], G[2p+1][j] },  p = adjacent-nm pair (0..7)
    v2f g2[4][8];
#pragma unroll
    for (int j = 0; j < 4; ++j)
#pragma unroll
        for (int p = 0; p < 8; ++p) g2[j][p] = (v2f){0.0f, 0.0f};

#define VISIT(R)                                                              \
    {                                                                         \
        float c[4], f[4];                                                     \
        edge_basis(R.x - pu.x, R.y - pu.y, c, f);                             \
        v2f f2[2] = { {f[0], f[1]}, {f[2], f[3]} };                           \
        float2 lo = h2f(R.z);                                                 \
        float2 hi = h2f(R.w);                                                 \
        float fvj[4] = {lo.x, lo.y, hi.x, hi.y};                              \
        _Pragma("unroll")                                                     \
        for (int n = 0; n < 4; ++n) {                                         \
            _Pragma("unroll")                                                 \
            for (int mh = 0; mh < 2; ++mh) {                                  \
                v2f w2 = c[n] * f2[mh];          /* 1 pk_mul */               \
                _Pragma("unroll")                                             \
                for (int j = 0; j < 4; ++j) {                                 \
                    v2f fb = { fvj[j], fvj[j] };                              \
                    g2[j][n * 2 + mh] =                                       \
                        __builtin_elementwise_fma(w2, fb, g2[j][n * 2 + mh]); \
                }                                                             \
            }                                                                 \
        }                                                                     \
    }

    if (cnt == 16) {
        int e0 = rs0 + eh * 8;
        const int4* nb4 = (const int4*)(neighbors + e0);
        int4 nA = nb4[0];
        int4 nB = nb4[1];

        // All 8 self-contained record loads issued before any compute:
        // 8-deep MLP window, 1 line per edge (pair lanes coalesce).
        float4 R0 = packed[nA.x * 2 + half];
        float4 R1 = packed[nA.y * 2 + half];
        float4 R2 = packed[nA.z * 2 + half];
        float4 R3 = packed[nA.w * 2 + half];
        float4 R4 = packed[nB.x * 2 + half];
        float4 R5 = packed[nB.y * 2 + half];
        float4 R6 = packed[nB.z * 2 + half];
        float4 R7 = packed[nB.w * 2 + half];

        VISIT(R0)
        VISIT(R1)
        VISIT(R2)
        VISIT(R3)
        VISIT(R4)
        VISIT(R5)
        VISIT(R6)
        VISIT(R7)
    } else {
        // Generic path (uniform DEG=16 never takes this; kept for safety).
        int c0 = (cnt + 1) >> 1;
        int e0 = rs0 + eh * c0;
        int e1 = (eh == 0) ? (rs0 + c0) : rs1;
        for (int e = e0; e < e1; ++e) {
            int nb = neighbors[e];
            float4 R = packed[nb * 2 + half];
            VISIT(R)
        }
    }
#undef VISIT

    // Final contraction: o[i] = sum_{j in half, nm} K[i, jg, nm] * G[nm][j]
    // acc pairs adjacent nm; the b128 K row supplies both pair halves.
    float o[8];
    const float4* K4 = (const float4*)Kl;
#pragma unroll
    for (int i = 0; i < 8; ++i) {
        v2f acc = (v2f){0.0f, 0.0f};
#pragma unroll
        for (int j = 0; j < 4; ++j) {
            int jg = half * 4 + j;
            int base4 = (i * 128 + jg * 16) >> 2;
#pragma unroll
            for (int q = 0; q < 4; ++q) {
                float4 kv = K4[base4 + q];
                v2f klo = { kv.x, kv.y };
                v2f khi = { kv.z, kv.w };
                acc = __builtin_elementwise_fma(klo, g2[j][2 * q],     acc);
                acc = __builtin_elementwise_fma(khi, g2[j][2 * q + 1], acc);
            }
        }
        o[i] = acc.x + acc.y;
    }

    // Reduce over the 4 lanes of this point (epilogue only — cheap).
#pragma unroll
    for (int i = 0; i < 8; ++i) {
        o[i] += __shfl_xor(o[i], 1);
        o[i] += __shfl_xor(o[i], 2);
    }

    float2 ov = (sub == 0) ? make_float2(o[0], o[1])
              : (sub == 1) ? make_float2(o[2], o[3])
              : (sub == 2) ? make_float2(o[4], o[5])
                           : make_float2(o[6], o[7]);
    ((float2*)out)[u * 4 + sub] = ov;
}

// ---- Fallback (no workspace): direct gathers, full fp32 (scalar math).
__global__ __launch_bounds__(256) void rbf_direct_kernel(
    const float* __restrict__ positions,
    const float* __restrict__ features,
    const float* __restrict__ kern,
    const int*   __restrict__ neighbors,
    const int*   __restrict__ row_splits,
    float*       __restrict__ out,
    int npts)
{
    __shared__ float Kl[1024];
    {
        const float4* src = (const float4*)kern;
        float4* dst = (float4*)Kl;
        dst[threadIdx.x] = src[threadIdx.x];
    }
    __syncthreads();

    int gt   = blockIdx.x * blockDim.x + threadIdx.x;
    int u    = gt >> 2;
    int sub  = gt & 3;
    int half = sub & 1;
    int eh   = sub >> 1;
    if (u >= npts) return;

    float2 pu = ((const float2*)positions)[u];
    int rs0 = row_splits[u];
    int rs1 = row_splits[u + 1];
    int cnt = rs1 - rs0;

    float g[16][4];
#pragma unroll
    for (int nm = 0; nm < 16; ++nm)
#pragma unroll
        for (int j = 0; j < 4; ++j) g[nm][j] = 0.0f;

    const float2* pos2  = (const float2*)positions;
    const float4* feat4 = (const float4*)features;

    int c0 = (cnt + 1) >> 1;
    int e0 = rs0 + eh * c0;
    int e1 = (eh == 0) ? (rs0 + c0) : rs1;
    for (int e = e0; e < e1; ++e) {
        int nb = neighbors[e];
        float2 pn = pos2[nb];
        float c[4], f[4];
        edge_basis(pn.x - pu.x, pn.y - pu.y, c, f);
        float4 fv = feat4[nb * 2 + half];
        float fvj[4] = {fv.x, fv.y, fv.z, fv.w};
#pragma unroll
        for (int n = 0; n < 4; ++n)
#pragma unroll
            for (int m = 0; m < 4; ++m) {
                float w = c[n] * f[m];
#pragma unroll
                for (int j = 0; j < 4; ++j)
                    g[n * 4 + m][j] = fmaf(w, fvj[j], g[n * 4 + m][j]);
            }
    }

    float o[8];
#pragma unroll
    for (int i = 0; i < 8; ++i) o[i] = 0.0f;
    const float4* K4 = (const float4*)Kl;
#pragma unroll
    for (int i = 0; i < 8; ++i) {
#pragma unroll
        for (int j = 0; j < 4; ++j) {
            int jg = half * 4 + j;
            int base4 = (i * 128 + jg * 16) >> 2;
#pragma unroll
            for (int q = 0; q < 4; ++q) {
                float4 kv = K4[base4 + q];
                o[i] = fmaf(kv.x, g[q * 4 + 0][j], o[i]);
                o[i] = fmaf(kv.y, g[q * 4 + 1][j], o[i]);
                o[i] = fmaf(kv.z, g[q * 4 + 2][j], o[i]);
                o[i] = fmaf(kv.w, g[q * 4 + 3][j], o[i]);
            }
        }
    }
#pragma unroll
    for (int i = 0; i < 8; ++i) {
        o[i] += __shfl_xor(o[i], 1);
        o[i] += __shfl_xor(o[i], 2);
    }
    float2 ov = (sub == 0) ? make_float2(o[0], o[1])
              : (sub == 1) ? make_float2(o[2], o[3])
              : (sub == 2) ? make_float2(o[4], o[5])
                           : make_float2(o[6], o[7]);
    ((float2*)out)[u * 4 + sub] = ov;
}

extern "C" void kernel_launch(void* const* d_in, const int* in_sizes, int n_in,
                              void* d_out, int out_size, void* d_ws, size_t ws_size,
                              hipStream_t stream) {
    const float* positions  = (const float*)d_in[0];
    const float* features   = (const float*)d_in[1];
    const float* kern       = (const float*)d_in[2];
    const int*   neighbors  = (const int*)d_in[3];
    const int*   row_splits = (const int*)d_in[4];
    float* out = (float*)d_out;

    int npts = in_sizes[0] / 2;
    int total = npts * 4;
    int block = 256;
    int grid = (total + block - 1) / block;

    size_t need = (size_t)npts * 32;   // 32B packed record per point
    if (ws_size >= need) {
        int pgrid = (npts + block - 1) / block;
        pack_kernel<<<pgrid, block, 0, stream>>>(positions, features,
                                                 (float4*)d_ws, npts);
        rbf_packed_kernel<<<grid, block, 0, stream>>>(positions,
                                                      (const float4*)d_ws, kern,
                                                      neighbors, row_splits,
                                                      out, npts);
    } else {
        rbf_direct_kernel<<<grid, block, 0, stream>>>(positions, features, kern,
                                                      neighbors, row_splits,
                                                      out, npts);
    }
}